// Round 1
// baseline (222.498 us; speedup 1.0000x reference)
//
#include <hip/hip_runtime.h>

#define IMG 512
#define TILE_W 64
#define TILE_H 32
#define IWID (TILE_W + 10)          // 74 intermediate cols (x-halo included)
#define LSTRIDE (IWID + 1)          // 75, odd => conflict-free LDS rows
#define NPIX_I (TILE_H * IWID)      // 2368 intermediate pixels per tile
#define NTHR 256
#define GRID_X (IMG / TILE_W)       // 8
#define GRID_Y (IMG / TILE_H)       // 16
#define GRID_Z 48                   // B*C = 16*3
#define NPART (GRID_X * GRID_Y * GRID_Z)   // 6144
#define INV_N (1.0f / 12582912.0f)  // 1/(16*3*512*512)

// Normalized 11-tap Gaussian, sigma=1.5 (matches reference _window2d)
#define GW_LIST {0.00102838f, 0.00759875f, 0.03600077f, 0.10936070f, \
                 0.21300554f, 0.26601173f, 0.21300554f, 0.10936070f, \
                 0.03600077f, 0.00759875f, 0.00102838f}

// Stage A: vertical Gaussian of the 5 product channels (t, i, t*t, i*i, t*i),
// reading global (L1-hot: tile input region ~25KB fits L1), writing LDS.
// GY: y-boundary guard needed only for first/last row of tiles.
template <bool GY>
__device__ __forceinline__ void stage_a(float* __restrict__ sm,
                                        const float* __restrict__ T,
                                        const float* __restrict__ I,
                                        int x0, int y0, int tid) {
    const float gw[11] = GW_LIST;
    for (int f = tid; f < NPIX_I; f += NTHR) {
        const int xi = f % IWID;
        const int yi = f / IWID;
        const int gx = x0 - 5 + xi;              // image column (may be OOB)
        float a0 = 0.f, a1 = 0.f, a2 = 0.f, a3 = 0.f, a4 = 0.f;
        if ((unsigned)gx < (unsigned)IMG) {      // OOB column => zero padding => sums stay 0
            const int gy0 = y0 + yi - 5;
            if (GY) {
                #pragma unroll
                for (int k = 0; k < 11; ++k) {
                    const int gy = gy0 + k;
                    const bool v = ((unsigned)gy < (unsigned)IMG);
                    const int gyc = v ? gy : 0;  // safe address
                    const float wk = v ? gw[k] : 0.f;
                    const float t = T[gyc * IMG + gx];
                    const float i = I[gyc * IMG + gx];
                    a0 += wk * t;       a1 += wk * i;
                    a2 += wk * (t * t); a3 += wk * (i * i); a4 += wk * (t * i);
                }
            } else {
                const float* tp = T + gy0 * IMG + gx;
                const float* ip = I + gy0 * IMG + gx;
                #pragma unroll
                for (int k = 0; k < 11; ++k) {
                    const float t = tp[k * IMG];
                    const float i = ip[k * IMG];
                    const float wk = gw[k];
                    a0 += wk * t;       a1 += wk * i;
                    a2 += wk * (t * t); a3 += wk * (i * i); a4 += wk * (t * i);
                }
            }
        }
        sm[(0 * TILE_H + yi) * LSTRIDE + xi] = a0;
        sm[(1 * TILE_H + yi) * LSTRIDE + xi] = a1;
        sm[(2 * TILE_H + yi) * LSTRIDE + xi] = a2;
        sm[(3 * TILE_H + yi) * LSTRIDE + xi] = a3;
        sm[(4 * TILE_H + yi) * LSTRIDE + xi] = a4;
    }
}

__global__ __launch_bounds__(NTHR, 3)
void ssim_main(const float* __restrict__ inp, const float* __restrict__ tgt,
               float* __restrict__ part) {
    __shared__ float sm[5 * TILE_H * LSTRIDE];   // 48000 B -> 3 blocks/CU
    __shared__ float rbuf[NTHR / 64];

    const int tid = threadIdx.x;
    const int x0 = blockIdx.x * TILE_W;
    const int ty = blockIdx.y;
    const int y0 = ty * TILE_H;
    const int bc = blockIdx.z;
    const float* T = tgt + (size_t)bc * (IMG * IMG);
    const float* I = inp + (size_t)bc * (IMG * IMG);

    if (ty == 0 || ty == GRID_Y - 1) stage_a<true >(sm, T, I, x0, y0, tid);
    else                             stage_a<false>(sm, T, I, x0, y0, tid);
    __syncthreads();

    // Stage B: horizontal Gaussian from LDS, 8 outputs per thread along x.
    const float gw[11] = GW_LIST;
    const int ly  = tid & 31;        // output row in tile
    const int seg = tid >> 5;        // 0..7
    const int xs  = seg * 8;         // local output x start

    float acc[5][8];
    #pragma unroll
    for (int c = 0; c < 5; ++c)
        #pragma unroll
        for (int r = 0; r < 8; ++r) acc[c][r] = 0.f;

    // output local X = xs + r uses intermediate cols X .. X+10
    const float* smrow = sm + ly * LSTRIDE + xs;
    #pragma unroll
    for (int c = 0; c < 18; ++c) {
        const float v0 = smrow[0 * TILE_H * LSTRIDE + c];
        const float v1 = smrow[1 * TILE_H * LSTRIDE + c];
        const float v2 = smrow[2 * TILE_H * LSTRIDE + c];
        const float v3 = smrow[3 * TILE_H * LSTRIDE + c];
        const float v4 = smrow[4 * TILE_H * LSTRIDE + c];
        #pragma unroll
        for (int r = 0; r < 8; ++r) {
            const int j = c - r;                 // tap index
            if (0 <= j && j < 11) {
                const float wk = gw[j];
                acc[0][r] += wk * v0;
                acc[1][r] += wk * v1;
                acc[2][r] += wk * v2;
                acc[3][r] += wk * v3;
                acc[4][r] += wk * v4;
            }
        }
    }

    // SSIM + mask + per-thread accumulation
    float lsum = 0.f;
    const float* trow = T + (y0 + ly) * IMG + (x0 + xs);   // raw target (mask), L1-hot
    #pragma unroll
    for (int r = 0; r < 8; ++r) {
        const float mu1 = acc[0][r], mu2 = acc[1][r];
        const float e11 = acc[2][r], e22 = acc[3][r], e12 = acc[4][r];
        const float m11 = mu1 * mu1, m22 = mu2 * mu2, m12 = mu1 * mu2;
        const float s1 = e11 - m11, s2 = e22 - m22, s12 = e12 - m12;
        const float num = (2.f * m12 + 1e-4f) * (2.f * s12 + 9e-4f);
        const float den = (m11 + m22 + 1e-4f) * (s1 + s2 + 9e-4f);
        const float ssim = __fdividef(num, den);
        lsum += (trow[r] > 0.f) ? (1.f - ssim) : 0.f;
    }

    // block reduction -> one partial per block (deterministic, no fp atomics)
    #pragma unroll
    for (int o = 32; o >= 1; o >>= 1) lsum += __shfl_down(lsum, o, 64);
    if ((tid & 63) == 0) rbuf[tid >> 6] = lsum;
    __syncthreads();
    if (tid == 0) {
        const int bid = (blockIdx.z * gridDim.y + blockIdx.y) * gridDim.x + blockIdx.x;
        part[bid] = rbuf[0] + rbuf[1] + rbuf[2] + rbuf[3];
    }
}

__global__ void ssim_reduce(const float* __restrict__ part, float* __restrict__ out) {
    __shared__ float rbuf[4];
    float s = 0.f;
    for (int i = threadIdx.x; i < NPART; i += 256) s += part[i];
    #pragma unroll
    for (int o = 32; o >= 1; o >>= 1) s += __shfl_down(s, o, 64);
    if ((threadIdx.x & 63) == 0) rbuf[threadIdx.x >> 6] = s;
    __syncthreads();
    if (threadIdx.x == 0) out[0] = (rbuf[0] + rbuf[1] + rbuf[2] + rbuf[3]) * INV_N;
}

extern "C" void kernel_launch(void* const* d_in, const int* in_sizes, int n_in,
                              void* d_out, int out_size, void* d_ws, size_t ws_size,
                              hipStream_t stream) {
    const float* inp = (const float*)d_in[0];   // "input"
    const float* tgt = (const float*)d_in[1];   // "target"
    float* out  = (float*)d_out;
    float* part = (float*)d_ws;                 // 6144 floats = 24 KB scratch

    dim3 grid(GRID_X, GRID_Y, GRID_Z);
    ssim_main<<<grid, NTHR, 0, stream>>>(inp, tgt, part);
    ssim_reduce<<<1, 256, 0, stream>>>(part, out);
}

// Round 3
// 162.590 us; speedup vs baseline: 1.3685x; 1.3685x over previous
//
#include <hip/hip_runtime.h>

typedef _Float16 half8 __attribute__((ext_vector_type(8)));
typedef float f32x4 __attribute__((ext_vector_type(4)));

#define IMG 512
#define NTHR 256
#define NBLK 12288              // 48 images x 256 blocks (block = 4 waves = 4 tiles of 16x16)
#define INV_N (1.0f / 12582912.0f)
#define C1c 1e-4f
#define C2c 9e-4f

// LDS (halves):
//  rawT[arr(2)][lx(80)][ly(40 pitch, 32 used)]  : transposed fp16 raw tiles, 6400 halves
//  v[wave(4)][ch(5)][m(16)][k(40 pitch, 32 used)]: vertical-pass output,      12800 halves
#define RAWIDX(arr, lx, ly) ((arr) * 3200 + (lx) * 40 + (ly))
#define VBASE(w) (6400 + (w) * 3200)
#define VIDX(c, m, k) ((c) * 640 + (m) * 40 + (k))

__global__ __launch_bounds__(NTHR, 4)
void ssim_mfma(const float* __restrict__ inp, const float* __restrict__ tgt,
               float* __restrict__ part)
{
    __shared__ _Float16 sm[19200];   // 38400 B -> 4 blocks/CU
    __shared__ float rbuf[4];

    const int tid = threadIdx.x;
    // XCD slab swizzle: consecutive work per XCD so halo re-reads hit the same L2
    const int B = blockIdx.x;
    const int W = (B & 7) * (NBLK / 8) + (B >> 3);
    const int bc  = W >> 8;          // image index 0..47
    const int rem = W & 255;
    const int ty = rem >> 3;         // 0..31, y tile row
    const int xb = rem & 7;          // 0..7, 64-wide x block
    const int X0 = xb * 64;
    const int y0 = ty * 16;

    const float* T = tgt + (size_t)bc * (IMG * IMG);
    const float* I = inp + (size_t)bc * (IMG * IMG);

    // ---- Stage raw tiles fp16, TRANSPOSED [x][y]: x in [X0-8, X0+72), y in [y0-5, y0+27)
    // 2 arrays x 20 xquads x 32 rows = 1280 float4 quads, 5 per thread; all boundaries
    // are float4-granular (X0-8 = 0 mod 4, image edges 0/512 = 0 mod 4).
    #pragma unroll
    for (int s = 0; s < 5; ++s) {
        const int qi = tid + s * NTHR;           // 0..1279
        const int arr = (qi >= 640) ? 1 : 0;     // arr switch at wave boundary
        const int r = qi - arr * 640;
        const int y  = r & 31;                   // consecutive lanes -> consecutive y
        const int xq = r >> 5;                   // 0..19
        const int gx = X0 - 8 + xq * 4;
        const int gy = y0 - 5 + y;
        float4 v = {0.f, 0.f, 0.f, 0.f};         // zero padding outside the image
        if ((unsigned)gy < (unsigned)IMG && (unsigned)gx < (unsigned)IMG) {
            const float* src = (arr ? I : T) + gy * IMG + gx;
            v = *(const float4*)src;
        }
        const int base = arr * 3200 + (xq * 4) * 40 + y;
        sm[base      ] = (_Float16)v.x;
        sm[base + 40 ] = (_Float16)v.y;
        sm[base + 80 ] = (_Float16)v.z;
        sm[base + 120] = (_Float16)v.w;
    }
    __syncthreads();

    const int w    = tid >> 6;       // wave id -> output x-tile X0 + w*16
    const int lane = tid & 63;
    const int n    = lane & 15;
    const int quad = lane >> 4;

    // Constant banded Gaussian fragment: element j holds w[(quad*8+j) - (lane&15)].
    // Serves as A[m][k]=w[k-m] in the vertical pass and B[k][n]=w[k-n] in the horizontal.
    half8 wf;
    #pragma unroll
    for (int j = 0; j < 8; ++j) {
        const int d = quad * 8 + j - n;
        const float x = (float)(d - 5);
        const float wd = __expf(-x * x * (1.0f / 4.5f)) * 0.26601173f; // normalized
        wf[j] = (_Float16)(((unsigned)d <= 10u) ? wd : 0.0f);
    }

    const int vb = VBASE(w);
    const f32x4 z = {0.f, 0.f, 0.f, 0.f};

    // ---- Vertical pass: two 16-wide v-tiles covering x-index k_h = 0..31 (x = x0w-5+k_h).
    // B-frag: lane reads 8 consecutive y at fixed x -> one ds_read_b128 from rawT.
    // lx clamp: columns k_h>=26 would read lx 80..82 (OOB). Their horizontal weight
    // w[k_h - n'] is identically zero (k_h-n' >= 11 for all n'<=15), so clamped
    // (wrong-but-FINITE) data contributes exactly 0. Never read OOB/uninit LDS (NaN x 0 = NaN).
    #pragma unroll
    for (int tt = 0; tt < 2; ++tt) {
        const int lxr = w * 16 + tt * 16 + n + 3;    // (x0w-5+tt*16+n) - (X0-8)
        const int lx = lxr > 79 ? 79 : lxr;
        const half8 tf = *(const half8*)&sm[RAWIDX(0, lx, quad * 8)];
        const half8 gf = *(const half8*)&sm[RAWIDX(1, lx, quad * 8)];
        const half8 t2 = tf * tf;
        const half8 g2 = gf * gf;
        const half8 tg = tf * gf;
        f32x4 d0 = __builtin_amdgcn_mfma_f32_16x16x32_f16(wf, tf, z, 0, 0, 0);
        f32x4 d1 = __builtin_amdgcn_mfma_f32_16x16x32_f16(wf, gf, z, 0, 0, 0);
        f32x4 d2 = __builtin_amdgcn_mfma_f32_16x16x32_f16(wf, t2, z, 0, 0, 0);
        f32x4 d3 = __builtin_amdgcn_mfma_f32_16x16x32_f16(wf, g2, z, 0, 0, 0);
        f32x4 d4 = __builtin_amdgcn_mfma_f32_16x16x32_f16(wf, tg, z, 0, 0, 0);
        // D layout: col = lane&15 (x within tile), row = quad*4+r (y). Store v row-major fp16.
        #pragma unroll
        for (int r = 0; r < 4; ++r) {
            const int m = quad * 4 + r;
            const int k = tt * 16 + n;
            sm[vb + VIDX(0, m, k)] = (_Float16)d0[r];
            sm[vb + VIDX(1, m, k)] = (_Float16)d1[r];
            sm[vb + VIDX(2, m, k)] = (_Float16)d2[r];
            sm[vb + VIDX(3, m, k)] = (_Float16)d3[r];
            sm[vb + VIDX(4, m, k)] = (_Float16)d4[r];
        }
    }
    // v crosses lanes within the wave (writer lane != reader lane): a barrier is
    // REQUIRED so the compiler cannot hoist the ds_reads above the ds_writes
    // (per-thread alias analysis sees distinct addresses and may legally reorder).
    __syncthreads();

    // ---- Horizontal pass: A-frag = v[m = lane&15][k = quad*8+j] (ds_read_b128), B = wf.
    const half8 a0 = *(const half8*)&sm[vb + VIDX(0, n, quad * 8)];
    const half8 a1 = *(const half8*)&sm[vb + VIDX(1, n, quad * 8)];
    const half8 a2 = *(const half8*)&sm[vb + VIDX(2, n, quad * 8)];
    const half8 a3 = *(const half8*)&sm[vb + VIDX(3, n, quad * 8)];
    const half8 a4 = *(const half8*)&sm[vb + VIDX(4, n, quad * 8)];
    const f32x4 mu1 = __builtin_amdgcn_mfma_f32_16x16x32_f16(a0, wf, z, 0, 0, 0);
    const f32x4 mu2 = __builtin_amdgcn_mfma_f32_16x16x32_f16(a1, wf, z, 0, 0, 0);
    const f32x4 e11 = __builtin_amdgcn_mfma_f32_16x16x32_f16(a2, wf, z, 0, 0, 0);
    const f32x4 e22 = __builtin_amdgcn_mfma_f32_16x16x32_f16(a3, wf, z, 0, 0, 0);
    const f32x4 e12 = __builtin_amdgcn_mfma_f32_16x16x32_f16(a4, wf, z, 0, 0, 0);

    // ---- SSIM epilogue: lane owns 4 px at (y0 + quad*4 + r, X0 + w*16 + n)
    float lsum = 0.f;
    #pragma unroll
    for (int r = 0; r < 4; ++r) {
        const int row = quad * 4 + r;
        const float tv = (float)sm[RAWIDX(0, w * 16 + n + 8, row + 5)];  // raw target (mask)
        const float m1 = mu1[r], m2 = mu2[r];
        const float m11 = m1 * m1, m22 = m2 * m2, m12 = m1 * m2;
        const float s1 = e11[r] - m11, s2 = e22[r] - m22, s12 = e12[r] - m12;
        const float num = (2.f * m12 + C1c) * (2.f * s12 + C2c);
        const float den = (m11 + m22 + C1c) * (s1 + s2 + C2c);
        lsum += (tv > 0.f) ? (1.f - __fdividef(num, den)) : 0.f;
    }

    // wave reduce -> block reduce -> one partial per block
    #pragma unroll
    for (int o = 32; o >= 1; o >>= 1) lsum += __shfl_down(lsum, o, 64);
    if (lane == 0) rbuf[w] = lsum;
    __syncthreads();
    if (tid == 0) part[B] = rbuf[0] + rbuf[1] + rbuf[2] + rbuf[3];
}

__global__ void ssim_reduce(const float* __restrict__ part, float* __restrict__ out) {
    __shared__ float rbuf[16];
    float s = 0.f;
    for (int i = threadIdx.x; i < NBLK; i += 1024) s += part[i];
    #pragma unroll
    for (int o = 32; o >= 1; o >>= 1) s += __shfl_down(s, o, 64);
    if ((threadIdx.x & 63) == 0) rbuf[threadIdx.x >> 6] = s;
    __syncthreads();
    if (threadIdx.x == 0) {
        float t = 0.f;
        #pragma unroll
        for (int k = 0; k < 16; ++k) t += rbuf[k];
        out[0] = t * INV_N;
    }
}

extern "C" void kernel_launch(void* const* d_in, const int* in_sizes, int n_in,
                              void* d_out, int out_size, void* d_ws, size_t ws_size,
                              hipStream_t stream) {
    const float* inp = (const float*)d_in[0];   // "input"
    const float* tgt = (const float*)d_in[1];   // "target"
    float* out  = (float*)d_out;
    float* part = (float*)d_ws;                 // 12288 floats = 48 KB scratch

    ssim_mfma<<<NBLK, NTHR, 0, stream>>>(inp, tgt, part);
    ssim_reduce<<<1, 1024, 0, stream>>>(part, out);
}